// Round 14
// baseline (245.037 us; speedup 1.0000x reference)
//
#include <hip/hip_runtime.h>
#include <math.h>

// XLNet two-stream relative attention — 4 dispatches:
//   prep_all -> big_gemm (fused q-scatter) -> attn_fused -> gemm_wo64 (fused gather)
// attn_fused now merges BOTH streams per block (8 waves, shared kc/kp staging).
// Input GEMMs bf16x2, out-proj bf16x3. B=2 S=1024 P=128 HID=1024 NH=16 DH=64

static constexpr int Bc  = 2;
static constexpr int Sc  = 1024;
static constexpr int Pc  = 128;
static constexpr int HIDc = 1024;
static constexpr int NHc = 16;
static constexpr int DHc = 64;

typedef __bf16 bf16;
typedef __bf16 bf16x8 __attribute__((ext_vector_type(8)));
typedef float  f32x4  __attribute__((ext_vector_type(4)));

#define MFMA16(a, b, c) __builtin_amdgcn_mfma_f32_16x16x32_bf16((a), (b), (c), 0, 0, 0)

// ---------------------------------------------------------------------------
// One prep dispatch: [0,256) seg bits (local sniff), [256,512) cmask bits,
// [512,768) qmask bits, [768,1024) find_idx, [1024,9344) splits, [9344,10368)
// zero qsf.
__global__ __launch_bounds__(256) void prep_all(
        const void* __restrict__ seg, const float* __restrict__ cm,
        const float* __restrict__ qm, const float* __restrict__ tm,
        const float* __restrict__ content, const float* __restrict__ posenc,
        const float* __restrict__ querys,
        const float* __restrict__ wq, const float* __restrict__ wkc,
        const float* __restrict__ wvp, const float* __restrict__ wkp,
        const float* __restrict__ wo,
        unsigned* __restrict__ segb, unsigned* __restrict__ cmb,
        unsigned* __restrict__ qmb,
        int* __restrict__ idxb, float* __restrict__ wgtb,
        bf16* __restrict__ ch, bf16* __restrict__ ph, bf16* __restrict__ qh,
        bf16* __restrict__ wqkvh, bf16* __restrict__ wqkvl,
        bf16* __restrict__ wkphh, bf16* __restrict__ wkpll,
        bf16* __restrict__ woh, bf16* __restrict__ wol,
        float* __restrict__ qsf) {
    __shared__ float tile[32][33];
    const int bid = blockIdx.x;
    const int tid = threadIdx.x;

    if (bid < 256) {
        __shared__ int sflag;
        if (tid == 0) sflag = 0;
        __syncthreads();
        {
            const unsigned char* sb8 = (const unsigned char*)seg;
            int f = 0;
            const int o = tid * 16;
#pragma unroll
            for (int i = 0; i < 16; ++i) {
                unsigned char c = sb8[o + i];
                int m = (o + i) & 3;
                if (m == 1 && c) f |= 1;
                if (m >= 2 && c) f |= 2;
            }
            if (f) atomicOr(&sflag, f);
        }
        __syncthreads();
        const int mode = (sflag & 1) ? 0 : ((sflag & 2) ? 2 : 1);
        const int idx = bid * 256 + tid;
        unsigned wv = 0;
        if (mode == 0) {
            const unsigned char* s = (const unsigned char*)seg + (size_t)idx * 32;
#pragma unroll
            for (int k = 0; k < 32; ++k) wv |= (s[k] != 0) ? (1u << k) : 0u;
        } else if (mode == 1) {
            const int* s = (const int*)seg + (size_t)idx * 32;
#pragma unroll
            for (int k = 0; k < 32; ++k) wv |= (s[k] != 0) ? (1u << k) : 0u;
        } else {
            const float* s = (const float*)seg + (size_t)idx * 32;
#pragma unroll
            for (int k = 0; k < 32; ++k) wv |= (s[k] != 0.f) ? (1u << k) : 0u;
        }
        segb[idx] = wv;
        return;
    }
    if (bid < 768) {
        const int which = (bid - 256) >> 8;
        const int idx = ((bid - 256) & 255) * 256 + tid;
        const float* s = (which == 0 ? cm : qm) + (size_t)idx * 32;
        unsigned wv = 0;
#pragma unroll
        for (int k = 0; k < 32; ++k) wv |= (s[k] != 0.f) ? (1u << k) : 0u;
        (which == 0 ? cmb : qmb)[idx] = wv;
        return;
    }
    if (bid < 1024) {
        const int bp = bid - 768;
        const float* row = tm + (size_t)bp * Sc;
        __shared__ int sidx;
        if (tid == 0) sidx = 0;
        __syncthreads();
        for (int j = tid; j < Sc; j += 256)
            if (row[j] != 0.f) atomicMax(&sidx, j);
        __syncthreads();
        if (tid == 0) { idxb[bp] = sidx; wgtb[bp] = row[sidx]; }
        return;
    }
    if (bid >= 9344) {
        const size_t i = ((size_t)(bid - 9344) * 256 + tid) * 8;
        float4 z = {0.f, 0.f, 0.f, 0.f};
        *(float4*)(qsf + i) = z;
        *(float4*)(qsf + i + 4) = z;
        return;
    }
    const int pb = bid - 1024;
    if (pb < 3200) {
        const float* src; bf16* hdst; size_t base;
        if (pb < 1024)      { src = content; hdst = ch; base = (size_t)pb * 2048; }
        else if (pb < 3072) { src = posenc;  hdst = ph; base = (size_t)(pb - 1024) * 2048; }
        else                { src = querys;  hdst = qh; base = (size_t)(pb - 3072) * 2048; }
        const size_t i = base + (size_t)tid * 8;
        float xs[8];
        *(float4*)xs       = *(const float4*)(src + i);
        *(float4*)(xs + 4) = *(const float4*)(src + i + 4);
        union { bf16 b[8]; uint4 u; } H;
#pragma unroll
        for (int k = 0; k < 8; ++k) H.b[k] = (bf16)xs[k];
        *(uint4*)(hdst + i) = H.u;
        return;
    }
    const int wid = pb - 3200;
    const int z = wid >> 10, rem = wid & 1023;
    const float* W = z == 0 ? wq : z == 1 ? wkc : z == 2 ? wvp : z == 3 ? wkp : wo;
    bf16* Th = z < 3 ? wqkvh + (size_t)z * HIDc * HIDc : (z == 3 ? wkphh : woh);
    bf16* Tl = z < 3 ? wqkvl + (size_t)z * HIDc * HIDc : (z == 3 ? wkpll : wol);
    const int k0 = (rem >> 5) * 32, n0 = (rem & 31) * 32;
    const int c = tid & 31, r0 = tid >> 5;
#pragma unroll
    for (int rr = 0; rr < 4; ++rr) {
        int r = r0 + rr * 8;
        tile[r][c] = W[(size_t)(k0 + r) * HIDc + n0 + c];
    }
    __syncthreads();
#pragma unroll
    for (int rr = 0; rr < 4; ++rr) {
        int n = r0 + rr * 8;
        float x = tile[c][n];
        bf16 hb = (bf16)x;
        Th[(size_t)(n0 + n) * HIDc + k0 + c] = hb;
        Tl[(size_t)(n0 + n) * HIDc + k0 + c] = (bf16)(x - (float)hb);
    }
}

// ---------------------------------------------------------------------------
// Merged input GEMMs, bf16x2, reg-prefetch pipelined, XCD-swizzled (656=8*82).
// Mode 0 (qg) scatters directly into qsf via target indices (atomicAdd).
__global__ __launch_bounds__(256) void big_gemm(
        const bf16* __restrict__ conth, const bf16* __restrict__ posh,
        const bf16* __restrict__ quh,
        const bf16* __restrict__ wqkvh, const bf16* __restrict__ wqkvl,
        const bf16* __restrict__ wkph, const bf16* __restrict__ wkpl,
        float* __restrict__ qf, bf16* __restrict__ kch,
        bf16* __restrict__ vtg, bf16* __restrict__ kpho,
        float* __restrict__ qsf, const int* __restrict__ idxb,
        const float* __restrict__ wgtb) {
    __shared__ bf16 AhS[128][40], BhS[128][40], BlS[128][40];
    const int bid = blockIdx.x;
    const int vb = (bid & 7) * 82 + (bid >> 3);
    int mode, bx, by;
    const bf16 *Ahp, *Bhp, *Blp;
    if (vb < 384)      { mode = 1; bx = vb >> 4; by = vb & 15;
                          Ahp = conth; Bhp = wqkvh; Blp = wqkvl; }
    else if (vb < 640) { mode = 2; int r = vb - 384; bx = r >> 5; by = r & 31;
                          Ahp = posh;  Bhp = wkph;  Blp = wkpl; }
    else               { mode = 0; int r = vb - 640; bx = r & 7; by = r >> 3;
                          Ahp = quh;   Bhp = wqkvh; Blp = wqkvl; }
    const int t = threadIdx.x, lane = t & 63, wv = t >> 6;
    const int g = lane >> 4, ml = lane & 15;
    const int m0 = by * 128, n0 = bx * 128;
    const int moff = (wv & 1) * 64, noff = (wv >> 1) * 64;
    const int row2 = t >> 1, c16 = (t & 1) * 16;
    const int K = HIDc;

    f32x4 acc[4][4];
#pragma unroll
    for (int i = 0; i < 4; ++i)
#pragma unroll
        for (int j = 0; j < 4; ++j) acc[i][j] = (f32x4){0.f, 0.f, 0.f, 0.f};

    uint4 rah0, rah1, rbh0, rbh1, rbl0, rbl1;
    auto gload = [&](int k0) {
        size_t ab = (size_t)(m0 + row2) * K + k0 + c16;
        rah0 = *(const uint4*)(Ahp + ab);
        rah1 = *(const uint4*)(Ahp + ab + 8);
        size_t bb = (size_t)(n0 + row2) * K + k0 + c16;
        rbh0 = *(const uint4*)(Bhp + bb);
        rbh1 = *(const uint4*)(Bhp + bb + 8);
        rbl0 = *(const uint4*)(Blp + bb);
        rbl1 = *(const uint4*)(Blp + bb + 8);
    };
    gload(0);

    for (int k0 = 0; k0 < K; k0 += 32) {
        __syncthreads();
        *(uint4*)&AhS[row2][c16]     = rah0;
        *(uint4*)&AhS[row2][c16 + 8] = rah1;
        *(uint4*)&BhS[row2][c16]     = rbh0;
        *(uint4*)&BhS[row2][c16 + 8] = rbh1;
        *(uint4*)&BlS[row2][c16]     = rbl0;
        *(uint4*)&BlS[row2][c16 + 8] = rbl1;
        __syncthreads();
        if (k0 + 32 < K) gload(k0 + 32);
        bf16x8 afh[4], bfh[4], bfl[4];
#pragma unroll
        for (int i = 0; i < 4; ++i) {
            afh[i] = *(const bf16x8*)&AhS[moff + i * 16 + ml][g * 8];
            bfh[i] = *(const bf16x8*)&BhS[noff + i * 16 + ml][g * 8];
            bfl[i] = *(const bf16x8*)&BlS[noff + i * 16 + ml][g * 8];
        }
#pragma unroll
        for (int i = 0; i < 4; ++i)
#pragma unroll
            for (int j = 0; j < 4; ++j) {
                acc[i][j] = MFMA16(afh[i], bfl[j], acc[i][j]);
                acc[i][j] = MFMA16(afh[i], bfh[j], acc[i][j]);
            }
    }
#pragma unroll
    for (int j = 0; j < 4; ++j) {
        const int nb = n0 + noff + j * 16;
#pragma unroll
        for (int i = 0; i < 4; ++i) {
            const int mbase = m0 + moff + i * 16 + g * 4;
            if (mode == 0) {
#pragma unroll
                for (int r = 0; r < 4; ++r) {
                    int p = mbase + r;
                    int qq = idxb[p];
                    float wgt = wgtb[p];
                    atomicAdd(&qsf[((size_t)((p >> 7) * Sc) + qq) * 1024 + nb + ml],
                              wgt * acc[i][j][r]);
                }
            } else if (mode == 2) {
                int hh = nb >> 6, d = (nb & 63) + ml;
#pragma unroll
                for (int r = 0; r < 4; ++r) {
                    int m = mbase + r, b = m >> 11, s = m & 2047;
                    kpho[((size_t)(b * 16 + hh) * 2048 + s) * 64 + d] = (bf16)acc[i][j][r];
                }
            } else {
                int reg = nb >> 10, nc = nb & 1023;
                if (reg == 0) {
#pragma unroll
                    for (int r = 0; r < 4; ++r)
                        qf[(size_t)(mbase + r) * 1024 + nc + ml] = acc[i][j][r];
                } else if (reg == 1) {
                    int hh = nc >> 6, d = (nc & 63) + ml;
#pragma unroll
                    for (int r = 0; r < 4; ++r) {
                        int m = mbase + r, b = m >> 10, s = m & 1023;
                        kch[((size_t)(b * 16 + hh) * 1024 + s) * 64 + d] = (bf16)acc[i][j][r];
                    }
                } else {
                    int hh = nc >> 6, d = (nc & 63) + ml;
                    int b = mbase >> 10, sb_ = mbase & 1023;
                    union { bf16 v[4]; uint2 u; } pk;
#pragma unroll
                    for (int r = 0; r < 4; ++r) pk.v[r] = (bf16)acc[i][j][r];
                    *(uint2*)(vtg + ((size_t)(b * 16 + hh) * 64 + d) * 1024 + sb_) = pk.u;
                }
            }
        }
    }
}

// ---------------------------------------------------------------------------
// Output projection, 64x128 tiles, both streams, one 288-block dispatch.
// Stream 2 gathers A rows from attn output via target indices.
__global__ __launch_bounds__(256) void gemm_wo64(
        const bf16* __restrict__ a1h, const bf16* __restrict__ a1l,
        const bf16* __restrict__ a2h, const bf16* __restrict__ a2l,
        const int* __restrict__ idxb, const float* __restrict__ wgtb,
        const bf16* __restrict__ Bhp, const bf16* __restrict__ Blp,
        float* __restrict__ out1, float* __restrict__ out2) {
    __shared__ bf16 AhS[64][40], AlS[64][40], BhS[128][40], BlS[128][40];
    const int bid = blockIdx.x;
    const int vb = (bid & 7) * 36 + (bid >> 3);
    float* Cf; int m0, n0; bool gat;
    if (vb < 256) { gat = false; Cf = out1; m0 = (vb & 31) * 64; n0 = (vb >> 5) * 128; }
    else          { int r = vb - 256; gat = true; Cf = out2;
                    m0 = (r & 3) * 64; n0 = (r >> 2) * 128; }
    const int t = threadIdx.x, lane = t & 63, wv = t >> 6;
    const int g = lane >> 4, ml = lane & 15;
    const int moff = (wv & 1) * 32, noff = (wv >> 1) * 64;
    const int arow = t >> 2, ac8 = (t & 3) * 8;
    const int brow = t >> 1, bc16 = (t & 1) * 16;
    const int K = HIDc, N = HIDc;

    size_t arow_base;
    float gw = 0.f;
    if (gat) {
        int p = m0 + arow;
        int qq = idxb[p];
        gw = wgtb[p];
        arow_base = ((size_t)((p >> 7) * Sc) + qq) * (size_t)K;
    } else {
        arow_base = (size_t)(m0 + arow) * K;
    }

    f32x4 acc[2][4];
#pragma unroll
    for (int i = 0; i < 2; ++i)
#pragma unroll
        for (int j = 0; j < 4; ++j) acc[i][j] = (f32x4){0.f, 0.f, 0.f, 0.f};

    uint4 rah, ral, rbh0, rbh1, rbl0, rbl1;
    auto gload = [&](int k0) {
        if (!gat) {
            rah = *(const uint4*)(a1h + arow_base + k0 + ac8);
            ral = *(const uint4*)(a1l + arow_base + k0 + ac8);
        } else {
            union { bf16 b[8]; uint4 u; } Hs, Ls, Ho, Lo;
            Hs.u = *(const uint4*)(a2h + arow_base + k0 + ac8);
            Ls.u = *(const uint4*)(a2l + arow_base + k0 + ac8);
#pragma unroll
            for (int e = 0; e < 8; ++e) {
                float v = ((float)Hs.b[e] + (float)Ls.b[e]) * gw;
                bf16 nh = (bf16)v;
                Ho.b[e] = nh;
                Lo.b[e] = (bf16)(v - (float)nh);
            }
            rah = Ho.u;
            ral = Lo.u;
        }
        size_t bo = (size_t)(n0 + brow) * K + k0 + bc16;
        rbh0 = *(const uint4*)(Bhp + bo);
        rbh1 = *(const uint4*)(Bhp + bo + 8);
        rbl0 = *(const uint4*)(Blp + bo);
        rbl1 = *(const uint4*)(Blp + bo + 8);
    };
    gload(0);

    for (int k0 = 0; k0 < K; k0 += 32) {
        __syncthreads();
        *(uint4*)&AhS[arow][ac8]      = rah;
        *(uint4*)&AlS[arow][ac8]      = ral;
        *(uint4*)&BhS[brow][bc16]     = rbh0;
        *(uint4*)&BhS[brow][bc16 + 8] = rbh1;
        *(uint4*)&BlS[brow][bc16]     = rbl0;
        *(uint4*)&BlS[brow][bc16 + 8] = rbl1;
        __syncthreads();
        if (k0 + 32 < K) gload(k0 + 32);
        bf16x8 afh[2], afl[2], bfh[4], bfl[4];
#pragma unroll
        for (int i = 0; i < 2; ++i) {
            afh[i] = *(const bf16x8*)&AhS[moff + i * 16 + ml][g * 8];
            afl[i] = *(const bf16x8*)&AlS[moff + i * 16 + ml][g * 8];
        }
#pragma unroll
        for (int j = 0; j < 4; ++j) {
            bfh[j] = *(const bf16x8*)&BhS[noff + j * 16 + ml][g * 8];
            bfl[j] = *(const bf16x8*)&BlS[noff + j * 16 + ml][g * 8];
        }
#pragma unroll
        for (int i = 0; i < 2; ++i)
#pragma unroll
            for (int j = 0; j < 4; ++j) {
                acc[i][j] = MFMA16(afl[i], bfh[j], acc[i][j]);
                acc[i][j] = MFMA16(afh[i], bfl[j], acc[i][j]);
                acc[i][j] = MFMA16(afh[i], bfh[j], acc[i][j]);
            }
    }
#pragma unroll
    for (int i = 0; i < 2; ++i)
#pragma unroll
        for (int j = 0; j < 4; ++j)
#pragma unroll
            for (int r = 0; r < 4; ++r)
                Cf[(size_t)(m0 + moff + i * 16 + g * 4 + r) * N + n0 + noff + j * 16 + ml] =
                    acc[i][j][r];
}

// ---------------------------------------------------------------------------
// Fused rel-attention, BOTH streams per block (512 blocks x 512 threads).
// Waves 0-3: content stream; waves 4-7: query stream — same (b,h,q0), shared
// kc double-buffer + kp 128-ring (staged once: waves 0-3 stage kc, 4-7 kp).
// One barrier/step. P in registers. m=0 softmax, ones-MFMA row sums.
__global__ __launch_bounds__(512, 2) void attn_fused(
        const float* __restrict__ qcf, const float* __restrict__ qqf,
        const bf16* __restrict__ kch, const bf16* __restrict__ vtg,
        const bf16* __restrict__ kph,
        const float* __restrict__ cb, const float* __restrict__ pb,
        const float* __restrict__ sb, const float* __restrict__ senc,
        const unsigned* __restrict__ sbits,
        const unsigned* __restrict__ cmb, const unsigned* __restrict__ qmb,
        bf16* __restrict__ aoh1, bf16* __restrict__ aol1,
        bf16* __restrict__ aoh2, bf16* __restrict__ aol2) {
    __shared__ bf16 kcS[2][32][72];
    __shared__ bf16 kpS[128][72];
    __shared__ float Rw[8][16][52];

    const int bid = blockIdx.x;
    const int vb = (bid & 7) * 64 + (bid >> 3);   // 512 = 8 XCD chunks of 64
    const int qb = vb & 15, h = (vb >> 4) & 15, b = vb >> 8;
    const int q0 = qb * 64;

    const int t = threadIdx.x;
    const int w8 = t >> 6;            // 0..7
    const int strm = w8 >> 2;         // 0: content, 1: query
    const int w = w8 & 3;             // wave within stream
    const int lane = t & 63, g = lane >> 4, ml = lane & 15;
    const float SCL2E = 0.125f * 1.44269504088896340736f;

    const float* qf = strm ? qqf : qcf;
    const unsigned* mbits = strm ? qmb : cmb;
    bf16* aoh = strm ? aoh2 : aoh1;
    bf16* aol = strm ? aol2 : aol1;

    // ---- q + biases -> pre-scaled fragments; segment dots (q = ml) ----
    const int qrow = q0 + w * 16 + ml;
    const float* qrp = qf + (size_t)(b * Sc + qrow) * HIDc + h * DHc;
    float qe[16], cbe[16], pbe[16], sbe[16], e0e[16], e1e[16];
    {
        const float* cbp = cb + h * DHc;
        const float* pbp = pb + h * DHc;
        const float* sbp = sb + h * DHc;
        const float* e0p = senc + h * DHc;
        const float* e1p = senc + NHc * DHc + h * DHc;
#pragma unroll
        for (int kk = 0; kk < 2; ++kk) {
            int o = kk * 32 + g * 8;
            *(float4*)(qe + kk * 8)      = *(const float4*)(qrp + o);
            *(float4*)(qe + kk * 8 + 4)  = *(const float4*)(qrp + o + 4);
            *(float4*)(cbe + kk * 8)     = *(const float4*)(cbp + o);
            *(float4*)(cbe + kk * 8 + 4) = *(const float4*)(cbp + o + 4);
            *(float4*)(pbe + kk * 8)     = *(const float4*)(pbp + o);
            *(float4*)(pbe + kk * 8 + 4) = *(const float4*)(pbp + o + 4);
            *(float4*)(sbe + kk * 8)     = *(const float4*)(sbp + o);
            *(float4*)(sbe + kk * 8 + 4) = *(const float4*)(sbp + o + 4);
            *(float4*)(e0e + kk * 8)     = *(const float4*)(e0p + o);
            *(float4*)(e0e + kk * 8 + 4) = *(const float4*)(e0p + o + 4);
            *(float4*)(e1e + kk * 8)     = *(const float4*)(e1p + o);
            *(float4*)(e1e + kk * 8 + 4) = *(const float4*)(e1p + o + 4);
        }
    }
    bf16x8 qch[2], qcl[2], qph[2], qpl[2];
    float s0 = 0.f, s1 = 0.f;
#pragma unroll
    for (int kk = 0; kk < 2; ++kk) {
#pragma unroll
        for (int i = 0; i < 8; ++i) {
            float qv = qe[kk * 8 + i];
            float xc = (qv + cbe[kk * 8 + i]) * SCL2E;
            float xp = (qv + pbe[kk * 8 + i]) * SCL2E;
            bf16 hb = (bf16)xc;
            qch[kk][i] = hb; qcl[kk][i] = (bf16)(xc - (float)hb);
            hb = (bf16)xp;
            qph[kk][i] = hb; qpl[kk][i] = (bf16)(xp - (float)hb);
            float qs = qv + sbe[kk * 8 + i];
            s0 += qs * e0e[kk * 8 + i];
            s1 += qs * e1e[kk * 8 + i];
        }
    }
    s0 += __shfl_xor(s0, 16); s0 += __shfl_xor(s0, 32);
    s1 += __shfl_xor(s1, 16); s1 += __shfl_xor(s1, 32);
    s0 *= SCL2E; s1 *= SCL2E;

    f32x4 oacc[4];
#pragma unroll
    for (int i = 0; i < 4; ++i) oacc[i] = (f32x4){0.f, 0.f, 0.f, 0.f};
    f32x4 lacc = (f32x4){0.f, 0.f, 0.f, 0.f};
    bf16x8 onesv;
#pragma unroll
    for (int i = 0; i < 8; ++i) onesv[i] = (bf16)1.0f;

    const size_t bh = (size_t)(b * 16 + h);
    const bf16* kcb = kch + bh * (Sc * DHc);
    const bf16* kpb = kph + bh * (2 * Sc * DHc);
    const bf16* vtb = vtg + bh * (DHc * Sc);
    const int woff = 48 - w * 16;
    const int base0 = Sc - q0 - 63;
    const size_t mrowq = (size_t)(b * Sc + qrow) * 32;

    // staging roles (wave-uniform): waves 0-3 stage kc, waves 4-7 stage kp
    const int ts = t & 255;                 // index within the staging half
    const int tr = ts >> 3, tc8 = (ts & 7) * 8;
    const int slot_tr = ((tr >> 2) & 1) * 16 + ((tr >> 3) << 2) + (tr & 3);

    uint4 pkc, pkp;
    if (strm == 0) {
        // kc tile 0 -> buf0; prefetch tile 1
        *(uint4*)&kcS[0][slot_tr][tc8] = *(const uint4*)(kcb + (size_t)tr * 64 + tc8);
        pkc = *(const uint4*)(kcb + (size_t)(32 + tr) * 64 + tc8);
    } else {
        // kp rows [base0, base0+95] -> ring; prefetch rows +96
#pragma unroll
        for (int e = 0; e < 3; ++e) {
            int grow = base0 + e * 32 + tr;
            *(uint4*)&kpS[grow & 127][tc8] = *(const uint4*)(kpb + (size_t)grow * 64 + tc8);
        }
        int gr = base0 + 96 + tr;
        gr = gr > 2 * Sc - 1 ? 2 * Sc - 1 : gr;
        pkp = *(const uint4*)(kpb + (size_t)gr * 64 + tc8);
    }
    int rb = (base0 + woff) & 127;
    int cur = 0;
    __syncthreads();

    for (int j0 = 0; j0 < Sc; j0 += 32) {
        // write prefetched tiles (disjoint from this step's reads)
        if (strm == 0) {
            *(uint4*)&kcS[cur ^ 1][slot_tr][tc8] = pkc;
            int nj = (j0 + 64 < Sc) ? j0 + 64 : 0;
            pkc = *(const uint4*)(kcb + (size_t)(nj + tr) * 64 + tc8);
        } else {
            int slot = (base0 + j0 + 96 + tr) & 127;
            *(uint4*)&kpS[slot][tc8] = pkp;
            int gr = base0 + j0 + 128 + tr;
            gr = gr > 2 * Sc - 1 ? 2 * Sc - 1 : gr;
            pkp = *(const uint4*)(kpb + (size_t)gr * 64 + tc8);
        }
        bf16x8 vfrag[4];
#pragma unroll
        for (int nt = 0; nt < 4; ++nt)
            vfrag[nt] = *(const bf16x8*)(vtb + (size_t)(nt * 16 + ml) * 1024 + j0 + g * 8);
        const int wcol = j0 >> 5;
        const unsigned mw = mbits[mrowq + wcol];
        const unsigned sw = sbits[mrowq + wcol];

        // ---- content scores (permuted slots, buf[cur]) ----
        f32x4 accc[2];
#pragma unroll
        for (int jt = 0; jt < 2; ++jt) {
            f32x4 a = (f32x4){0.f, 0.f, 0.f, 0.f};
#pragma unroll
            for (int kk = 0; kk < 2; ++kk) {
                bf16x8 kf = *(const bf16x8*)&kcS[cur][jt * 16 + ml][kk * 32 + g * 8];
                a = MFMA16(kf, qcl[kk], a);
                a = MFMA16(kf, qch[kk], a);
            }
            accc[jt] = a;
        }
        // ---- position band from ring -> Rw (vector write) ----
#pragma unroll
        for (int ct = 0; ct < 3; ++ct) {
            int row = (rb + ct * 16 + ml) & 127;
            f32x4 a = (f32x4){0.f, 0.f, 0.f, 0.f};
#pragma unroll
            for (int kk = 0; kk < 2; ++kk) {
                bf16x8 kfp = *(const bf16x8*)&kpS[row][kk * 32 + g * 8];
                a = MFMA16(kfp, qpl[kk], a);
                a = MFMA16(kfp, qph[kk], a);
            }
            *(f32x4*)&Rw[w8][ml][ct * 16 + g * 4] = a;
        }
        rb = (rb + 32) & 127;

        // ---- P = exp2(scaled s) in registers; masked -> 0 ----
        bf16x8 pa;
#pragma unroll
        for (int jt = 0; jt < 2; ++jt) {
#pragma unroll
            for (int r = 0; r < 4; ++r) {
                int jl = g * 8 + jt * 4 + r;
                float s = accc[jt][r] + Rw[w8][ml][jl - ml + 15] +
                          (((sw >> jl) & 1u) ? s1 : s0);
                float p = exp2f(s);
                p = ((mw >> jl) & 1u) ? 0.f : p;
                pa[jt * 4 + r] = (bf16)p;
            }
        }

        // ---- PV + row sums ----
#pragma unroll
        for (int nt = 0; nt < 4; ++nt)
            oacc[nt] = MFMA16(pa, vfrag[nt], oacc[nt]);
        lacc = MFMA16(pa, onesv, lacc);

        cur ^= 1;
        __syncthreads();
    }

    float inv[4];
#pragma unroll
    for (int r = 0; r < 4; ++r) inv[r] = 1.0f / lacc[r];
#pragma unroll
    for (int nt = 0; nt < 4; ++nt)
#pragma unroll
        for (int r = 0; r < 4; ++r) {
            float val = oacc[nt][r] * inv[r];
            size_t o = (size_t)(b * Sc + q0 + w * 16 + g * 4 + r) * HIDc + h * DHc + nt * 16 + ml;
            bf16 hb = (bf16)val;
            aoh[o] = hb;
            aol[o] = (bf16)(val - (float)hb);
        }
}

// ---------------------------------------------------------------------------
extern "C" void kernel_launch(void* const* d_in, const int* in_sizes, int n_in,
                              void* d_out, int out_size, void* d_ws, size_t ws_size,
                              hipStream_t stream) {
    const float* content = (const float*)d_in[0];
    const float* querys  = (const float*)d_in[1];
    const float* posenc  = (const float*)d_in[2];
    const void*  segraw  = d_in[3];
    const float* senc    = (const float*)d_in[4];
    const float* sbias   = (const float*)d_in[5];
    const float* cmask   = (const float*)d_in[6];
    const float* qmask   = (const float*)d_in[7];
    const float* tmap    = (const float*)d_in[8];
    const float* cbias   = (const float*)d_in[9];
    const float* pbias   = (const float*)d_in[10];
    const float* wq      = (const float*)d_in[11];
    const float* wkc     = (const float*)d_in[12];
    const float* wv      = (const float*)d_in[13];
    const float* wkp     = (const float*)d_in[14];
    const float* wo      = (const float*)d_in[15];
    float* out = (float*)d_out;

    char* ws = (char*)d_ws;
    size_t off = 0;
    auto take = [&](size_t bytes) -> char* {
        char* p = ws + off;
        off += (bytes + 255) & ~(size_t)255;
        return p;
    };
    int*      idxb = (int*)take(Bc * Pc * 4);
    float*    wgtb = (float*)take(Bc * Pc * 4);
    unsigned* segb = (unsigned*)take((size_t)Bc * Sc * 32 * 4);
    unsigned* cmb  = (unsigned*)take((size_t)Bc * Sc * 32 * 4);
    unsigned* qmb  = (unsigned*)take((size_t)Bc * Sc * 32 * 4);
    bf16* wqkvh = (bf16*)take((size_t)3 * HIDc * HIDc * 2);
    bf16* wqkvl = (bf16*)take((size_t)3 * HIDc * HIDc * 2);
    bf16* wkphw = (bf16*)take((size_t)HIDc * HIDc * 2);
    bf16* wkplw = (bf16*)take((size_t)HIDc * HIDc * 2);
    bf16* woh   = (bf16*)take((size_t)HIDc * HIDc * 2);
    bf16* wol   = (bf16*)take((size_t)HIDc * HIDc * 2);
    bf16* conth = (bf16*)take((size_t)Bc * Sc * HIDc * 2);
    bf16* posh  = (bf16*)take((size_t)Bc * 2 * Sc * HIDc * 2);
    bf16* quh   = (bf16*)take((size_t)Bc * Pc * HIDc * 2);
    float* qf   = (float*)take((size_t)Bc * Sc * HIDc * 4);
    float* qsf  = (float*)take((size_t)Bc * Sc * HIDc * 4);
    bf16* kchp  = (bf16*)take((size_t)Bc * NHc * Sc * DHc * 2);
    bf16* kphp  = (bf16*)take((size_t)Bc * NHc * 2 * Sc * DHc * 2);
    bf16* vtg   = (bf16*)take((size_t)Bc * NHc * DHc * Sc * 2);
    bf16* aoh1  = (bf16*)take((size_t)Bc * Sc * HIDc * 2);
    bf16* aol1  = (bf16*)take((size_t)Bc * Sc * HIDc * 2);
    bf16* aoh2  = (bf16*)take((size_t)Bc * Sc * HIDc * 2);
    bf16* aol2  = (bf16*)take((size_t)Bc * Sc * HIDc * 2);

    dim3 blk(256);

    prep_all<<<10368, blk, 0, stream>>>(segraw, cmask, qmask, tmap,
                                        content, posenc, querys,
                                        wq, wkc, wv, wkp, wo,
                                        segb, cmb, qmb, idxb, wgtb,
                                        conth, posh, quh,
                                        wqkvh, wqkvl, wkphw, wkplw, woh, wol,
                                        qsf);

    big_gemm<<<656, blk, 0, stream>>>(conth, posh, quh,
                                      wqkvh, wqkvl, wkphw, wkplw,
                                      qf, kchp, vtg, kphp,
                                      qsf, idxb, wgtb);

    attn_fused<<<512, dim3(512), 0, stream>>>(qf, qsf, kchp, vtg, kphp,
                                              cbias, pbias, sbias, senc, segb, cmb, qmb,
                                              aoh1, aol1, aoh2, aol2);

    gemm_wo64<<<288, blk, 0, stream>>>(aoh1, aol1, aoh2, aol2, idxb, wgtb,
                                       woh, wol,
                                       out, out + (size_t)Bc * Sc * HIDc);
}

// Round 15
// 223.985 us; speedup vs baseline: 1.0940x; 1.0940x over previous
//
#include <hip/hip_runtime.h>
#include <math.h>

// XLNet two-stream relative attention — 4 dispatches total:
//   prep_all -> big_gemm (fused q-scatter) -> attn_fused -> gemm_wo64 (fused gather)
// Input GEMMs bf16x2, out-proj bf16x3. Fused MFMA attention: swapped score
// MFMA, kc slot-permuted double-buffered LDS, kp 128-ring, one barrier/step,
// P in registers, m=0 softmax, ones-MFMA row sums.  (R13 best config, 224 µs)
// B=2 S=1024 P=128 HID=1024 NH=16 DH=64

static constexpr int Bc  = 2;
static constexpr int Sc  = 1024;
static constexpr int Pc  = 128;
static constexpr int HIDc = 1024;
static constexpr int NHc = 16;
static constexpr int DHc = 64;

typedef __bf16 bf16;
typedef __bf16 bf16x8 __attribute__((ext_vector_type(8)));
typedef float  f32x4  __attribute__((ext_vector_type(4)));

#define MFMA16(a, b, c) __builtin_amdgcn_mfma_f32_16x16x32_bf16((a), (b), (c), 0, 0, 0)

// ---------------------------------------------------------------------------
// One prep dispatch: [0,256) seg bits (local sniff), [256,512) cmask bits,
// [512,768) qmask bits, [768,1024) find_idx, [1024,9344) splits, [9344,10368)
// zero qsf.
__global__ __launch_bounds__(256) void prep_all(
        const void* __restrict__ seg, const float* __restrict__ cm,
        const float* __restrict__ qm, const float* __restrict__ tm,
        const float* __restrict__ content, const float* __restrict__ posenc,
        const float* __restrict__ querys,
        const float* __restrict__ wq, const float* __restrict__ wkc,
        const float* __restrict__ wvp, const float* __restrict__ wkp,
        const float* __restrict__ wo,
        unsigned* __restrict__ segb, unsigned* __restrict__ cmb,
        unsigned* __restrict__ qmb,
        int* __restrict__ idxb, float* __restrict__ wgtb,
        bf16* __restrict__ ch, bf16* __restrict__ ph, bf16* __restrict__ qh,
        bf16* __restrict__ wqkvh, bf16* __restrict__ wqkvl,
        bf16* __restrict__ wkphh, bf16* __restrict__ wkpll,
        bf16* __restrict__ woh, bf16* __restrict__ wol,
        float* __restrict__ qsf) {
    __shared__ float tile[32][33];
    const int bid = blockIdx.x;
    const int tid = threadIdx.x;

    if (bid < 256) {
        __shared__ int sflag;
        if (tid == 0) sflag = 0;
        __syncthreads();
        {
            const unsigned char* sb8 = (const unsigned char*)seg;
            int f = 0;
            const int o = tid * 16;
#pragma unroll
            for (int i = 0; i < 16; ++i) {
                unsigned char c = sb8[o + i];
                int m = (o + i) & 3;
                if (m == 1 && c) f |= 1;
                if (m >= 2 && c) f |= 2;
            }
            if (f) atomicOr(&sflag, f);
        }
        __syncthreads();
        const int mode = (sflag & 1) ? 0 : ((sflag & 2) ? 2 : 1);
        const int idx = bid * 256 + tid;
        unsigned wv = 0;
        if (mode == 0) {
            const unsigned char* s = (const unsigned char*)seg + (size_t)idx * 32;
#pragma unroll
            for (int k = 0; k < 32; ++k) wv |= (s[k] != 0) ? (1u << k) : 0u;
        } else if (mode == 1) {
            const int* s = (const int*)seg + (size_t)idx * 32;
#pragma unroll
            for (int k = 0; k < 32; ++k) wv |= (s[k] != 0) ? (1u << k) : 0u;
        } else {
            const float* s = (const float*)seg + (size_t)idx * 32;
#pragma unroll
            for (int k = 0; k < 32; ++k) wv |= (s[k] != 0.f) ? (1u << k) : 0u;
        }
        segb[idx] = wv;
        return;
    }
    if (bid < 768) {
        const int which = (bid - 256) >> 8;
        const int idx = ((bid - 256) & 255) * 256 + tid;
        const float* s = (which == 0 ? cm : qm) + (size_t)idx * 32;
        unsigned wv = 0;
#pragma unroll
        for (int k = 0; k < 32; ++k) wv |= (s[k] != 0.f) ? (1u << k) : 0u;
        (which == 0 ? cmb : qmb)[idx] = wv;
        return;
    }
    if (bid < 1024) {
        const int bp = bid - 768;
        const float* row = tm + (size_t)bp * Sc;
        __shared__ int sidx;
        if (tid == 0) sidx = 0;
        __syncthreads();
        for (int j = tid; j < Sc; j += 256)
            if (row[j] != 0.f) atomicMax(&sidx, j);
        __syncthreads();
        if (tid == 0) { idxb[bp] = sidx; wgtb[bp] = row[sidx]; }
        return;
    }
    if (bid >= 9344) {
        const size_t i = ((size_t)(bid - 9344) * 256 + tid) * 8;
        float4 z = {0.f, 0.f, 0.f, 0.f};
        *(float4*)(qsf + i) = z;
        *(float4*)(qsf + i + 4) = z;
        return;
    }
    const int pb = bid - 1024;
    if (pb < 3200) {
        const float* src; bf16* hdst; size_t base;
        if (pb < 1024)      { src = content; hdst = ch; base = (size_t)pb * 2048; }
        else if (pb < 3072) { src = posenc;  hdst = ph; base = (size_t)(pb - 1024) * 2048; }
        else                { src = querys;  hdst = qh; base = (size_t)(pb - 3072) * 2048; }
        const size_t i = base + (size_t)tid * 8;
        float xs[8];
        *(float4*)xs       = *(const float4*)(src + i);
        *(float4*)(xs + 4) = *(const float4*)(src + i + 4);
        union { bf16 b[8]; uint4 u; } H;
#pragma unroll
        for (int k = 0; k < 8; ++k) H.b[k] = (bf16)xs[k];
        *(uint4*)(hdst + i) = H.u;
        return;
    }
    const int wid = pb - 3200;
    const int z = wid >> 10, rem = wid & 1023;
    const float* W = z == 0 ? wq : z == 1 ? wkc : z == 2 ? wvp : z == 3 ? wkp : wo;
    bf16* Th = z < 3 ? wqkvh + (size_t)z * HIDc * HIDc : (z == 3 ? wkphh : woh);
    bf16* Tl = z < 3 ? wqkvl + (size_t)z * HIDc * HIDc : (z == 3 ? wkpll : wol);
    const int k0 = (rem >> 5) * 32, n0 = (rem & 31) * 32;
    const int c = tid & 31, r0 = tid >> 5;
#pragma unroll
    for (int rr = 0; rr < 4; ++rr) {
        int r = r0 + rr * 8;
        tile[r][c] = W[(size_t)(k0 + r) * HIDc + n0 + c];
    }
    __syncthreads();
#pragma unroll
    for (int rr = 0; rr < 4; ++rr) {
        int n = r0 + rr * 8;
        float x = tile[c][n];
        bf16 hb = (bf16)x;
        Th[(size_t)(n0 + n) * HIDc + k0 + c] = hb;
        Tl[(size_t)(n0 + n) * HIDc + k0 + c] = (bf16)(x - (float)hb);
    }
}

// ---------------------------------------------------------------------------
// Merged input GEMMs, bf16x2, reg-prefetch pipelined, XCD-swizzled (656=8*82).
// Mode 0 (qg) scatters directly into qsf via target indices (atomicAdd).
__global__ __launch_bounds__(256) void big_gemm(
        const bf16* __restrict__ conth, const bf16* __restrict__ posh,
        const bf16* __restrict__ quh,
        const bf16* __restrict__ wqkvh, const bf16* __restrict__ wqkvl,
        const bf16* __restrict__ wkph, const bf16* __restrict__ wkpl,
        float* __restrict__ qf, bf16* __restrict__ kch,
        bf16* __restrict__ vtg, bf16* __restrict__ kpho,
        float* __restrict__ qsf, const int* __restrict__ idxb,
        const float* __restrict__ wgtb) {
    __shared__ bf16 AhS[128][40], BhS[128][40], BlS[128][40];
    const int bid = blockIdx.x;
    const int vb = (bid & 7) * 82 + (bid >> 3);
    int mode, bx, by;
    const bf16 *Ahp, *Bhp, *Blp;
    if (vb < 384)      { mode = 1; bx = vb >> 4; by = vb & 15;
                          Ahp = conth; Bhp = wqkvh; Blp = wqkvl; }
    else if (vb < 640) { mode = 2; int r = vb - 384; bx = r >> 5; by = r & 31;
                          Ahp = posh;  Bhp = wkph;  Blp = wkpl; }
    else               { mode = 0; int r = vb - 640; bx = r & 7; by = r >> 3;
                          Ahp = quh;   Bhp = wqkvh; Blp = wqkvl; }
    const int t = threadIdx.x, lane = t & 63, wv = t >> 6;
    const int g = lane >> 4, ml = lane & 15;
    const int m0 = by * 128, n0 = bx * 128;
    const int moff = (wv & 1) * 64, noff = (wv >> 1) * 64;
    const int row2 = t >> 1, c16 = (t & 1) * 16;
    const int K = HIDc;

    f32x4 acc[4][4];
#pragma unroll
    for (int i = 0; i < 4; ++i)
#pragma unroll
        for (int j = 0; j < 4; ++j) acc[i][j] = (f32x4){0.f, 0.f, 0.f, 0.f};

    uint4 rah0, rah1, rbh0, rbh1, rbl0, rbl1;
    auto gload = [&](int k0) {
        size_t ab = (size_t)(m0 + row2) * K + k0 + c16;
        rah0 = *(const uint4*)(Ahp + ab);
        rah1 = *(const uint4*)(Ahp + ab + 8);
        size_t bb = (size_t)(n0 + row2) * K + k0 + c16;
        rbh0 = *(const uint4*)(Bhp + bb);
        rbh1 = *(const uint4*)(Bhp + bb + 8);
        rbl0 = *(const uint4*)(Blp + bb);
        rbl1 = *(const uint4*)(Blp + bb + 8);
    };
    gload(0);

    for (int k0 = 0; k0 < K; k0 += 32) {
        __syncthreads();
        *(uint4*)&AhS[row2][c16]     = rah0;
        *(uint4*)&AhS[row2][c16 + 8] = rah1;
        *(uint4*)&BhS[row2][c16]     = rbh0;
        *(uint4*)&BhS[row2][c16 + 8] = rbh1;
        *(uint4*)&BlS[row2][c16]     = rbl0;
        *(uint4*)&BlS[row2][c16 + 8] = rbl1;
        __syncthreads();
        if (k0 + 32 < K) gload(k0 + 32);
        bf16x8 afh[4], bfh[4], bfl[4];
#pragma unroll
        for (int i = 0; i < 4; ++i) {
            afh[i] = *(const bf16x8*)&AhS[moff + i * 16 + ml][g * 8];
            bfh[i] = *(const bf16x8*)&BhS[noff + i * 16 + ml][g * 8];
            bfl[i] = *(const bf16x8*)&BlS[noff + i * 16 + ml][g * 8];
        }
#pragma unroll
        for (int i = 0; i < 4; ++i)
#pragma unroll
            for (int j = 0; j < 4; ++j) {
                acc[i][j] = MFMA16(afh[i], bfl[j], acc[i][j]);
                acc[i][j] = MFMA16(afh[i], bfh[j], acc[i][j]);
            }
    }
#pragma unroll
    for (int j = 0; j < 4; ++j) {
        const int nb = n0 + noff + j * 16;
#pragma unroll
        for (int i = 0; i < 4; ++i) {
            const int mbase = m0 + moff + i * 16 + g * 4;
            if (mode == 0) {
#pragma unroll
                for (int r = 0; r < 4; ++r) {
                    int p = mbase + r;
                    int qq = idxb[p];
                    float wgt = wgtb[p];
                    atomicAdd(&qsf[((size_t)((p >> 7) * Sc) + qq) * 1024 + nb + ml],
                              wgt * acc[i][j][r]);
                }
            } else if (mode == 2) {
                int hh = nb >> 6, d = (nb & 63) + ml;
#pragma unroll
                for (int r = 0; r < 4; ++r) {
                    int m = mbase + r, b = m >> 11, s = m & 2047;
                    kpho[((size_t)(b * 16 + hh) * 2048 + s) * 64 + d] = (bf16)acc[i][j][r];
                }
            } else {
                int reg = nb >> 10, nc = nb & 1023;
                if (reg == 0) {
#pragma unroll
                    for (int r = 0; r < 4; ++r)
                        qf[(size_t)(mbase + r) * 1024 + nc + ml] = acc[i][j][r];
                } else if (reg == 1) {
                    int hh = nc >> 6, d = (nc & 63) + ml;
#pragma unroll
                    for (int r = 0; r < 4; ++r) {
                        int m = mbase + r, b = m >> 10, s = m & 1023;
                        kch[((size_t)(b * 16 + hh) * 1024 + s) * 64 + d] = (bf16)acc[i][j][r];
                    }
                } else {
                    int hh = nc >> 6, d = (nc & 63) + ml;
                    int b = mbase >> 10, sb_ = mbase & 1023;
                    union { bf16 v[4]; uint2 u; } pk;
#pragma unroll
                    for (int r = 0; r < 4; ++r) pk.v[r] = (bf16)acc[i][j][r];
                    *(uint2*)(vtg + ((size_t)(b * 16 + hh) * 64 + d) * 1024 + sb_) = pk.u;
                }
            }
        }
    }
}

// ---------------------------------------------------------------------------
// Output projection, 64x128 tiles, both streams, one 288-block dispatch.
// Stream 2 gathers A rows from attn output via target indices (fused gather_o).
__global__ __launch_bounds__(256) void gemm_wo64(
        const bf16* __restrict__ a1h, const bf16* __restrict__ a1l,
        const bf16* __restrict__ a2h, const bf16* __restrict__ a2l,
        const int* __restrict__ idxb, const float* __restrict__ wgtb,
        const bf16* __restrict__ Bhp, const bf16* __restrict__ Blp,
        float* __restrict__ out1, float* __restrict__ out2) {
    __shared__ bf16 AhS[64][40], AlS[64][40], BhS[128][40], BlS[128][40];
    const int bid = blockIdx.x;
    const int vb = (bid & 7) * 36 + (bid >> 3);
    float* Cf; int m0, n0; bool gat;
    if (vb < 256) { gat = false; Cf = out1; m0 = (vb & 31) * 64; n0 = (vb >> 5) * 128; }
    else          { int r = vb - 256; gat = true; Cf = out2;
                    m0 = (r & 3) * 64; n0 = (r >> 2) * 128; }
    const int t = threadIdx.x, lane = t & 63, wv = t >> 6;
    const int g = lane >> 4, ml = lane & 15;
    const int moff = (wv & 1) * 32, noff = (wv >> 1) * 64;
    const int arow = t >> 2, ac8 = (t & 3) * 8;
    const int brow = t >> 1, bc16 = (t & 1) * 16;
    const int K = HIDc, N = HIDc;

    size_t arow_base;
    float gw = 0.f;
    if (gat) {
        int p = m0 + arow;
        int qq = idxb[p];
        gw = wgtb[p];
        arow_base = ((size_t)((p >> 7) * Sc) + qq) * (size_t)K;
    } else {
        arow_base = (size_t)(m0 + arow) * K;
    }

    f32x4 acc[2][4];
#pragma unroll
    for (int i = 0; i < 2; ++i)
#pragma unroll
        for (int j = 0; j < 4; ++j) acc[i][j] = (f32x4){0.f, 0.f, 0.f, 0.f};

    uint4 rah, ral, rbh0, rbh1, rbl0, rbl1;
    auto gload = [&](int k0) {
        if (!gat) {
            rah = *(const uint4*)(a1h + arow_base + k0 + ac8);
            ral = *(const uint4*)(a1l + arow_base + k0 + ac8);
        } else {
            union { bf16 b[8]; uint4 u; } Hs, Ls, Ho, Lo;
            Hs.u = *(const uint4*)(a2h + arow_base + k0 + ac8);
            Ls.u = *(const uint4*)(a2l + arow_base + k0 + ac8);
#pragma unroll
            for (int e = 0; e < 8; ++e) {
                float v = ((float)Hs.b[e] + (float)Ls.b[e]) * gw;
                bf16 nh = (bf16)v;
                Ho.b[e] = nh;
                Lo.b[e] = (bf16)(v - (float)nh);
            }
            rah = Ho.u;
            ral = Lo.u;
        }
        size_t bo = (size_t)(n0 + brow) * K + k0 + bc16;
        rbh0 = *(const uint4*)(Bhp + bo);
        rbh1 = *(const uint4*)(Bhp + bo + 8);
        rbl0 = *(const uint4*)(Blp + bo);
        rbl1 = *(const uint4*)(Blp + bo + 8);
    };
    gload(0);

    for (int k0 = 0; k0 < K; k0 += 32) {
        __syncthreads();
        *(uint4*)&AhS[arow][ac8]      = rah;
        *(uint4*)&AlS[arow][ac8]      = ral;
        *(uint4*)&BhS[brow][bc16]     = rbh0;
        *(uint4*)&BhS[brow][bc16 + 8] = rbh1;
        *(uint4*)&BlS[brow][bc16]     = rbl0;
        *(uint4*)&BlS[brow][bc16 + 8] = rbl1;
        __syncthreads();
        if (k0 + 32 < K) gload(k0 + 32);
        bf16x8 afh[2], afl[2], bfh[4], bfl[4];
#pragma unroll
        for (int i = 0; i < 2; ++i) {
            afh[i] = *(const bf16x8*)&AhS[moff + i * 16 + ml][g * 8];
            afl[i] = *(const bf16x8*)&AlS[moff + i * 16 + ml][g * 8];
        }
#pragma unroll
        for (int j = 0; j < 4; ++j) {
            bfh[j] = *(const bf16x8*)&BhS[noff + j * 16 + ml][g * 8];
            bfl[j] = *(const bf16x8*)&BlS[noff + j * 16 + ml][g * 8];
        }
#pragma unroll
        for (int i = 0; i < 2; ++i)
#pragma unroll
            for (int j = 0; j < 4; ++j) {
                acc[i][j] = MFMA16(afl[i], bfh[j], acc[i][j]);
                acc[i][j] = MFMA16(afh[i], bfl[j], acc[i][j]);
                acc[i][j] = MFMA16(afh[i], bfh[j], acc[i][j]);
            }
    }
#pragma unroll
    for (int i = 0; i < 2; ++i)
#pragma unroll
        for (int j = 0; j < 4; ++j)
#pragma unroll
            for (int r = 0; r < 4; ++r)
                Cf[(size_t)(m0 + moff + i * 16 + g * 4 + r) * N + n0 + noff + j * 16 + ml] =
                    acc[i][j][r];
}

// ---------------------------------------------------------------------------
// Fused rel-attention (R12/R13 config). Both streams, 1024 blocks, 4 waves x
// 16 q-rows, j=32. kc slot-permuted double-buffered LDS; kp 128-row ring;
// one barrier/step; P in registers; m=0 softmax; ones-MFMA row sums.
__global__ __launch_bounds__(256, 4) void attn_fused(
        const float* __restrict__ qcf, const float* __restrict__ qqf,
        const bf16* __restrict__ kch, const bf16* __restrict__ vtg,
        const bf16* __restrict__ kph,
        const float* __restrict__ cb, const float* __restrict__ pb,
        const float* __restrict__ sb, const float* __restrict__ senc,
        const unsigned* __restrict__ sbits,
        const unsigned* __restrict__ cmb, const unsigned* __restrict__ qmb,
        bf16* __restrict__ aoh1, bf16* __restrict__ aol1,
        bf16* __restrict__ aoh2, bf16* __restrict__ aol2) {
    __shared__ bf16 kcS[2][32][72];
    __shared__ bf16 kpS[128][72];
    __shared__ float Rw[4][16][52];

    const int bid = blockIdx.x;
    const int vb = (bid & 7) * 128 + (bid >> 3);
    const int qb = vb & 15, strm = (vb >> 4) & 1, h = (vb >> 5) & 15, b = vb >> 9;
    const int q0 = qb * 64;

    const float* qf = strm ? qqf : qcf;
    const unsigned* mbits = strm ? qmb : cmb;
    bf16* aoh = strm ? aoh2 : aoh1;
    bf16* aol = strm ? aol2 : aol1;

    const int t = threadIdx.x, w = t >> 6, lane = t & 63, g = lane >> 4, ml = lane & 15;
    const float SCL2E = 0.125f * 1.44269504088896340736f;

    const int qrow = q0 + w * 16 + ml;
    const float* qrp = qf + (size_t)(b * Sc + qrow) * HIDc + h * DHc;
    float qe[16], cbe[16], pbe[16], sbe[16], e0e[16], e1e[16];
    {
        const float* cbp = cb + h * DHc;
        const float* pbp = pb + h * DHc;
        const float* sbp = sb + h * DHc;
        const float* e0p = senc + h * DHc;
        const float* e1p = senc + NHc * DHc + h * DHc;
#pragma unroll
        for (int kk = 0; kk < 2; ++kk) {
            int o = kk * 32 + g * 8;
            *(float4*)(qe + kk * 8)      = *(const float4*)(qrp + o);
            *(float4*)(qe + kk * 8 + 4)  = *(const float4*)(qrp + o + 4);
            *(float4*)(cbe + kk * 8)     = *(const float4*)(cbp + o);
            *(float4*)(cbe + kk * 8 + 4) = *(const float4*)(cbp + o + 4);
            *(float4*)(pbe + kk * 8)     = *(const float4*)(pbp + o);
            *(float4*)(pbe + kk * 8 + 4) = *(const float4*)(pbp + o + 4);
            *(float4*)(sbe + kk * 8)     = *(const float4*)(sbp + o);
            *(float4*)(sbe + kk * 8 + 4) = *(const float4*)(sbp + o + 4);
            *(float4*)(e0e + kk * 8)     = *(const float4*)(e0p + o);
            *(float4*)(e0e + kk * 8 + 4) = *(const float4*)(e0p + o + 4);
            *(float4*)(e1e + kk * 8)     = *(const float4*)(e1p + o);
            *(float4*)(e1e + kk * 8 + 4) = *(const float4*)(e1p + o + 4);
        }
    }
    bf16x8 qch[2], qcl[2], qph[2], qpl[2];
    float s0 = 0.f, s1 = 0.f;
#pragma unroll
    for (int kk = 0; kk < 2; ++kk) {
#pragma unroll
        for (int i = 0; i < 8; ++i) {
            float qv = qe[kk * 8 + i];
            float xc = (qv + cbe[kk * 8 + i]) * SCL2E;
            float xp = (qv + pbe[kk * 8 + i]) * SCL2E;
            bf16 hb = (bf16)xc;
            qch[kk][i] = hb; qcl[kk][i] = (bf16)(xc - (float)hb);
            hb = (bf16)xp;
            qph[kk][i] = hb; qpl[kk][i] = (bf16)(xp - (float)hb);
            float qs = qv + sbe[kk * 8 + i];
            s0 += qs * e0e[kk * 8 + i];
            s1 += qs * e1e[kk * 8 + i];
        }
    }
    s0 += __shfl_xor(s0, 16); s0 += __shfl_xor(s0, 32);
    s1 += __shfl_xor(s1, 16); s1 += __shfl_xor(s1, 32);
    s0 *= SCL2E; s1 *= SCL2E;

    f32x4 oacc[4];
#pragma unroll
    for (int i = 0; i < 4; ++i) oacc[i] = (f32x4){0.f, 0.f, 0.f, 0.f};
    f32x4 lacc = (f32x4){0.f, 0.f, 0.f, 0.f};
    bf16x8 onesv;
#pragma unroll
    for (int i = 0; i < 8; ++i) onesv[i] = (bf16)1.0f;

    const size_t bh = (size_t)(b * 16 + h);
    const bf16* kcb = kch + bh * (Sc * DHc);
    const bf16* kpb = kph + bh * (2 * Sc * DHc);
    const bf16* vtb = vtg + bh * (DHc * Sc);
    const int woff = 48 - w * 16;
    const int base0 = Sc - q0 - 63;
    const size_t mrowq = (size_t)(b * Sc + qrow) * 32;

    const int tr = t >> 3, tc8 = (t & 7) * 8;
    const int slot_tr = ((tr >> 2) & 1) * 16 + ((tr >> 3) << 2) + (tr & 3);

    *(uint4*)&kcS[0][slot_tr][tc8] = *(const uint4*)(kcb + (size_t)tr * 64 + tc8);
#pragma unroll
    for (int e = 0; e < 3; ++e) {
        int grow = base0 + e * 32 + tr;
        *(uint4*)&kpS[grow & 127][tc8] = *(const uint4*)(kpb + (size_t)grow * 64 + tc8);
    }
    uint4 pkc, pkp;
    pkc = *(const uint4*)(kcb + (size_t)(32 + tr) * 64 + tc8);
    {
        int gr = base0 + 96 + tr;
        gr = gr > 2 * Sc - 1 ? 2 * Sc - 1 : gr;
        pkp = *(const uint4*)(kpb + (size_t)gr * 64 + tc8);
    }
    int rb = (base0 + woff) & 127;
    int cur = 0;
    __syncthreads();

    for (int j0 = 0; j0 < Sc; j0 += 32) {
        *(uint4*)&kcS[cur ^ 1][slot_tr][tc8] = pkc;
        {
            int slot = (base0 + j0 + 96 + tr) & 127;
            *(uint4*)&kpS[slot][tc8] = pkp;
        }
        {
            int nj = (j0 + 64 < Sc) ? j0 + 64 : 0;
            pkc = *(const uint4*)(kcb + (size_t)(nj + tr) * 64 + tc8);
            int gr = base0 + j0 + 128 + tr;
            gr = gr > 2 * Sc - 1 ? 2 * Sc - 1 : gr;
            pkp = *(const uint4*)(kpb + (size_t)gr * 64 + tc8);
        }
        bf16x8 vfrag[4];
#pragma unroll
        for (int nt = 0; nt < 4; ++nt)
            vfrag[nt] = *(const bf16x8*)(vtb + (size_t)(nt * 16 + ml) * 1024 + j0 + g * 8);
        const int wcol = j0 >> 5;
        const unsigned mw = mbits[mrowq + wcol];
        const unsigned sw = sbits[mrowq + wcol];

        f32x4 accc[2];
#pragma unroll
        for (int jt = 0; jt < 2; ++jt) {
            f32x4 a = (f32x4){0.f, 0.f, 0.f, 0.f};
#pragma unroll
            for (int kk = 0; kk < 2; ++kk) {
                bf16x8 kf = *(const bf16x8*)&kcS[cur][jt * 16 + ml][kk * 32 + g * 8];
                a = MFMA16(kf, qcl[kk], a);
                a = MFMA16(kf, qch[kk], a);
            }
            accc[jt] = a;
        }
#pragma unroll
        for (int ct = 0; ct < 3; ++ct) {
            int row = (rb + ct * 16 + ml) & 127;
            f32x4 a = (f32x4){0.f, 0.f, 0.f, 0.f};
#pragma unroll
            for (int kk = 0; kk < 2; ++kk) {
                bf16x8 kfp = *(const bf16x8*)&kpS[row][kk * 32 + g * 8];
                a = MFMA16(kfp, qpl[kk], a);
                a = MFMA16(kfp, qph[kk], a);
            }
            *(f32x4*)&Rw[w][ml][ct * 16 + g * 4] = a;
        }
        rb = (rb + 32) & 127;

        bf16x8 pa;
#pragma unroll
        for (int jt = 0; jt < 2; ++jt) {
#pragma unroll
            for (int r = 0; r < 4; ++r) {
                int jl = g * 8 + jt * 4 + r;
                float s = accc[jt][r] + Rw[w][ml][jl - ml + 15] +
                          (((sw >> jl) & 1u) ? s1 : s0);
                float p = exp2f(s);
                p = ((mw >> jl) & 1u) ? 0.f : p;
                pa[jt * 4 + r] = (bf16)p;
            }
        }

#pragma unroll
        for (int nt = 0; nt < 4; ++nt)
            oacc[nt] = MFMA16(pa, vfrag[nt], oacc[nt]);
        lacc = MFMA16(pa, onesv, lacc);

        cur ^= 1;
        __syncthreads();
    }

    float inv[4];
#pragma unroll
    for (int r = 0; r < 4; ++r) inv[r] = 1.0f / lacc[r];
#pragma unroll
    for (int nt = 0; nt < 4; ++nt)
#pragma unroll
        for (int r = 0; r < 4; ++r) {
            float val = oacc[nt][r] * inv[r];
            size_t o = (size_t)(b * Sc + q0 + w * 16 + g * 4 + r) * HIDc + h * DHc + nt * 16 + ml;
            bf16 hb = (bf16)val;
            aoh[o] = hb;
            aol[o] = (bf16)(val - (float)hb);
        }
}

// ---------------------------------------------------------------------------
extern "C" void kernel_launch(void* const* d_in, const int* in_sizes, int n_in,
                              void* d_out, int out_size, void* d_ws, size_t ws_size,
                              hipStream_t stream) {
    const float* content = (const float*)d_in[0];
    const float* querys  = (const float*)d_in[1];
    const float* posenc  = (const float*)d_in[2];
    const void*  segraw  = d_in[3];
    const float* senc    = (const float*)d_in[4];
    const float* sbias   = (const float*)d_in[5];
    const float* cmask   = (const float*)d_in[6];
    const float* qmask   = (const float*)d_in[7];
    const float* tmap    = (const float*)d_in[8];
    const float* cbias   = (const float*)d_in[9];
    const float* pbias   = (const float*)d_in[10];
    const float* wq      = (const float*)d_in[11];
    const float* wkc     = (const float*)d_in[12];
    const float* wv      = (const float*)d_in[13];
    const float* wkp     = (const float*)d_in[14];
    const float* wo      = (const float*)d_in[15];
    float* out = (float*)d_out;

    char* ws = (char*)d_ws;
    size_t off = 0;
    auto take = [&](size_t bytes) -> char* {
        char* p = ws + off;
        off += (bytes + 255) & ~(size_t)255;
        return p;
    };
    int*      idxb = (int*)take(Bc * Pc * 4);
    float*    wgtb = (float*)take(Bc * Pc * 4);
    unsigned* segb = (unsigned*)take((size_t)Bc * Sc * 32 * 4);
    unsigned* cmb  = (unsigned*)take((size_t)Bc * Sc * 32 * 4);
    unsigned* qmb  = (unsigned*)take((size_t)Bc * Sc * 32 * 4);
    bf16* wqkvh = (bf16*)take((size_t)3 * HIDc * HIDc * 2);
    bf16* wqkvl = (bf16*)take((size_t)3 * HIDc * HIDc * 2);
    bf16* wkphw = (bf16*)take((size_t)HIDc * HIDc * 2);
    bf16* wkplw = (bf16*)take((size_t)HIDc * HIDc * 2);
    bf16* woh   = (bf16*)take((size_t)HIDc * HIDc * 2);
    bf16* wol   = (bf16*)take((size_t)HIDc * HIDc * 2);
    bf16* conth = (bf16*)take((size_t)Bc * Sc * HIDc * 2);
    bf16* posh  = (bf16*)take((size_t)Bc * 2 * Sc * HIDc * 2);
    bf16* quh   = (bf16*)take((size_t)Bc * Pc * HIDc * 2);
    float* qf   = (float*)take((size_t)Bc * Sc * HIDc * 4);
    float* qsf  = (float*)take((size_t)Bc * Sc * HIDc * 4);
    bf16* kchp  = (bf16*)take((size_t)Bc * NHc * Sc * DHc * 2);
    bf16* kphp  = (bf16*)take((size_t)Bc * NHc * 2 * Sc * DHc * 2);
    bf16* vtg   = (bf16*)take((size_t)Bc * NHc * DHc * Sc * 2);
    bf16* aoh1  = (bf16*)take((size_t)Bc * Sc * HIDc * 2);
    bf16* aol1  = (bf16*)take((size_t)Bc * Sc * HIDc * 2);
    bf16* aoh2  = (bf16*)take((size_t)Bc * Sc * HIDc * 2);
    bf16* aol2  = (bf16*)take((size_t)Bc * Sc * HIDc * 2);

    dim3 blk(256);

    prep_all<<<10368, blk, 0, stream>>>(segraw, cmask, qmask, tmap,
                                        content, posenc, querys,
                                        wq, wkc, wv, wkp, wo,
                                        segb, cmb, qmb, idxb, wgtb,
                                        conth, posh, quh,
                                        wqkvh, wqkvl, wkphw, wkplw, woh, wol,
                                        qsf);

    big_gemm<<<656, blk, 0, stream>>>(conth, posh, quh,
                                      wqkvh, wqkvl, wkphw, wkplw,
                                      qf, kchp, vtg, kphp,
                                      qsf, idxb, wgtb);

    attn_fused<<<1024, blk, 0, stream>>>(qf, qsf, kchp, vtg, kphp,
                                         cbias, pbias, sbias, senc, segb, cmb, qmb,
                                         aoh1, aol1, aoh2, aol2);

    gemm_wo64<<<288, blk, 0, stream>>>(aoh1, aol1, aoh2, aol2, idxb, wgtb,
                                       woh, wol,
                                       out, out + (size_t)Bc * Sc * HIDc);
}